// Round 3
// baseline (879.441 us; speedup 1.0000x reference)
//
#include <hip/hip_runtime.h>
#include <hip/hip_bf16.h>

#define cN0 500000
#define cN1 100000
#define cN2 25000
#define cE0 1600000
#define cE1 400000

typedef __bf16 bf16x8 __attribute__((ext_vector_type(8)));
typedef __bf16 bf16x4 __attribute__((ext_vector_type(4)));
typedef float f32x4 __attribute__((ext_vector_type(4)));

// ---------------- CSR build ----------------

__global__ void k_hist(const int* __restrict__ dst, int E, int* __restrict__ cnt) {
    int i = blockIdx.x * blockDim.x + threadIdx.x;
    if (i < E) atomicAdd(&cnt[dst[i]], 1);
}

__global__ void k_scan1(int* __restrict__ a, int n, int* __restrict__ bsum) {
    __shared__ int lds[256];
    const int t = threadIdx.x;
    const int base = blockIdx.x * 1024 + t * 4;
    int v0 = (base + 0 < n) ? a[base + 0] : 0;
    int v1 = (base + 1 < n) ? a[base + 1] : 0;
    int v2 = (base + 2 < n) ? a[base + 2] : 0;
    int v3 = (base + 3 < n) ? a[base + 3] : 0;
    const int s = v0 + v1 + v2 + v3;
    lds[t] = s;
    __syncthreads();
    int x = s;
    for (int d = 1; d < 256; d <<= 1) {
        int y = (t >= d) ? lds[t - d] : 0;
        __syncthreads();
        x += y;
        lds[t] = x;
        __syncthreads();
    }
    if (t == 255) bsum[blockIdx.x] = x;
    int e0 = x - s;
    int e1 = e0 + v0, e2 = e1 + v1, e3 = e2 + v2;
    if (base + 0 < n) a[base + 0] = e0;
    if (base + 1 < n) a[base + 1] = e1;
    if (base + 2 < n) a[base + 2] = e2;
    if (base + 3 < n) a[base + 3] = e3;
}

__global__ void k_scan2(int* __restrict__ bsum, int nb) {
    __shared__ int lds[128];
    const int t = threadIdx.x;
    int v = (t < nb) ? bsum[t] : 0;
    lds[t] = v;
    __syncthreads();
    int x = v;
    for (int d = 1; d < 128; d <<= 1) {
        int y = (t >= d) ? lds[t - d] : 0;
        __syncthreads();
        x += y;
        lds[t] = x;
        __syncthreads();
    }
    if (t < nb) bsum[t] = x - v;
}

// add block offsets AND emit the scatter cursor copy in one pass
__global__ void k_scan3(int* __restrict__ a, int n, const int* __restrict__ bsum, int total,
                        int* __restrict__ cur) {
    int i = blockIdx.x * blockDim.x + threadIdx.x;
    if (i < n) {
        int v = a[i] + bsum[i >> 10];
        a[i] = v;
        cur[i] = v;
    }
    if (i == 0) a[n] = total;
}

__global__ void k_scatter(const int* __restrict__ esrc, const int* __restrict__ edst, int E,
                          int* __restrict__ cur, int* __restrict__ srcs) {
    int i = blockIdx.x * blockDim.x + threadIdx.x;
    if (i < E) {
        int p = atomicAdd(&cur[edst[i]], 1);
        srcs[p] = esrc[i];
    }
}

// ---------------- x fp32 -> bf16 table ----------------
__global__ __launch_bounds__(256) void k_cast(const float* __restrict__ x,
                                              __bf16* __restrict__ xb, int n8) {
    int i = blockIdx.x * blockDim.x + threadIdx.x;
    if (i < n8) {
        const float4 v0 = *(const float4*)(x + (size_t)i * 8);
        const float4 v1 = *(const float4*)(x + (size_t)i * 8 + 4);
        bf16x8 o;
        o[0] = (__bf16)v0.x; o[1] = (__bf16)v0.y; o[2] = (__bf16)v0.z; o[3] = (__bf16)v0.w;
        o[4] = (__bf16)v1.x; o[5] = (__bf16)v1.y; o[6] = (__bf16)v1.z; o[7] = (__bf16)v1.w;
        *(bf16x8*)(xb + (size_t)i * 8) = o;
    }
}

// ---------------- weight concat (fp32 -> bf16) ----------------
__global__ void k_wcat0(const float* __restrict__ Wl, const float* __restrict__ Wr,
                        __bf16* __restrict__ Wc) {
    int i = blockIdx.x * blockDim.x + threadIdx.x;   // 256*256
    if (i < 256 * 256) {
        int j = i >> 8, k = i & 255;
        float v = (k < 128) ? Wl[j * 128 + k] : Wr[j * 128 + (k - 128)];
        Wc[i] = (__bf16)v;
    }
}
__global__ void k_wcat1(const float* __restrict__ Wl, const float* __restrict__ Wr,
                        __bf16* __restrict__ Wc) {
    int i = blockIdx.x * blockDim.x + threadIdx.x;   // 128*512
    if (i < 128 * 512) {
        int j = i >> 9, k = i & 511;
        float v = (k < 256) ? Wl[j * 256 + k] : Wr[j * 256 + (k - 256)];
        Wc[i] = (__bf16)v;
    }
}

// ---------------- hop0 aggregation: Agg0[g] = bf16(mean xb_src) ----------------
// wave = 4 edge-slots x 16 dim-lanes (16B bf16x8/lane); 8 nodes per wave.
__global__ __launch_bounds__(256) void k_agg0(
    const __bf16* __restrict__ xb,
    const int* __restrict__ off, const int* __restrict__ srcs,
    const __bf16* __restrict__ zrow,
    __bf16* __restrict__ Agg)
{
    const int wid = blockIdx.x * 4 + (threadIdx.x >> 6);
    const int lane = threadIdx.x & 63;
    const int slot = lane >> 4;          // 0..3
    const int dl = lane & 15;            // dims dl*8 .. dl*8+7
    const int gbase = wid * 8;
    for (int n = 0; n < 8; ++n) {
        const int g = gbase + n;
        if (g >= cN1) return;
        const int e0 = off[g], e1 = off[g + 1];
        const int deg = e1 - e0;
        float a[8] = {0.f, 0.f, 0.f, 0.f, 0.f, 0.f, 0.f, 0.f};
        const int iters = (deg + 3) >> 2;
        for (int it = 0; it < iters; ++it) {
            const int e = e0 + it * 4 + slot;
            const __bf16* rp = zrow;
            if (e < e1) rp = xb + (size_t)srcs[e] * 128;
            const bf16x8 r = *(const bf16x8*)(rp + dl * 8);
            #pragma unroll
            for (int d = 0; d < 8; ++d) a[d] += (float)r[d];
        }
        #pragma unroll
        for (int d = 0; d < 8; ++d) {
            a[d] += __shfl_xor(a[d], 16);
            a[d] += __shfl_xor(a[d], 32);
        }
        if (slot == 0) {
            const float inv = 1.f / (float)(deg > 0 ? deg : 1);
            bf16x8 o;
            #pragma unroll
            for (int d = 0; d < 8; ++d) o[d] = (__bf16)(a[d] * inv);
            *(bf16x8*)(Agg + (size_t)g * 128 + dl * 8) = o;
        }
    }
}

// ---------------- hop1 aggregation: Agg1[g] = bf16(mean h_src) ----------------
// wave = 2 edge-slots x 32 dim-lanes; 4 nodes per wave.
__global__ __launch_bounds__(256) void k_agg1(
    const __bf16* __restrict__ h,
    const int* __restrict__ off, const int* __restrict__ srcs,
    const __bf16* __restrict__ zrow,
    __bf16* __restrict__ Agg)
{
    const int wid = blockIdx.x * 4 + (threadIdx.x >> 6);
    const int lane = threadIdx.x & 63;
    const int slot = lane >> 5;          // 0..1
    const int dl = lane & 31;            // dims dl*8 .. dl*8+7
    const int gbase = wid * 4;
    for (int n = 0; n < 4; ++n) {
        const int g = gbase + n;
        if (g >= cN2) return;
        const int e0 = off[g], e1 = off[g + 1];
        const int deg = e1 - e0;
        float a[8] = {0.f, 0.f, 0.f, 0.f, 0.f, 0.f, 0.f, 0.f};
        const int iters = (deg + 1) >> 1;
        for (int it = 0; it < iters; ++it) {
            const int e = e0 + it * 2 + slot;
            const __bf16* rp = zrow;
            if (e < e1) rp = h + (size_t)srcs[e] * 256;
            const bf16x8 r = *(const bf16x8*)(rp + dl * 8);
            #pragma unroll
            for (int d = 0; d < 8; ++d) a[d] += (float)r[d];
        }
        #pragma unroll
        for (int d = 0; d < 8; ++d) a[d] += __shfl_xor(a[d], 32);
        if (slot == 0) {
            const float inv = 1.f / (float)(deg > 0 ? deg : 1);
            bf16x8 o;
            #pragma unroll
            for (int d = 0; d < 8; ++d) o[d] = (__bf16)(a[d] * inv);
            *(bf16x8*)(Agg + (size_t)g * 256 + dl * 8) = o;
        }
    }
}

// ---------------- bf16 MFMA GEMM: C = act([A1|A2][Mrows x 2*KHALF] @ W^T + bias) ----------------
// A1 = aggregated half (pitch KHALF), A2 = root half (pitch KHALF), W [N x 2*KHALF].
// block = 4 waves, tile 128(M) x 128(N); wave = 64x64 via 4x4 of 16x16x32 MFMA.
template<int KHALF, int LDC, bool RELU, bool OUTBF16>
__global__ __launch_bounds__(256) void k_gemm(
    const __bf16* __restrict__ A1, const __bf16* __restrict__ A2,
    const __bf16* __restrict__ W, const float* __restrict__ bias,
    float* __restrict__ outf, __bf16* __restrict__ outb, int Mrows)
{
    const int K = KHALF * 2;
    const int tid = threadIdx.x;
    const int l = tid & 63;
    const int w = tid >> 6;
    const int wm = w & 1, wn = w >> 1;
    const int row0 = blockIdx.x * 128 + wm * 64;
    const int col0 = blockIdx.y * 128 + wn * 64;
    const int lr = l & 15;
    const int lk = (l >> 4) * 8;

    const __bf16* pa1[4];
    const __bf16* pa2[4];
    const __bf16* pb[4];
    #pragma unroll
    for (int i = 0; i < 4; ++i) {
        int r = row0 + i * 16 + lr;
        r = (r < Mrows) ? r : (Mrows - 1);
        pa1[i] = A1 + (size_t)r * KHALF + lk;
        pa2[i] = A2 + (size_t)r * KHALF + lk;
        pb[i] = W + (size_t)(col0 + i * 16 + lr) * K + lk;
    }
    f32x4 acc[4][4];
    #pragma unroll
    for (int i = 0; i < 4; ++i)
        #pragma unroll
        for (int j = 0; j < 4; ++j)
            acc[i][j] = (f32x4)0.0f;

    #pragma unroll 2
    for (int k0 = 0; k0 < KHALF; k0 += 32) {
        bf16x8 fa[4], fb[4];
        #pragma unroll
        for (int i = 0; i < 4; ++i) fa[i] = *(const bf16x8*)(pa1[i] + k0);
        #pragma unroll
        for (int j = 0; j < 4; ++j) fb[j] = *(const bf16x8*)(pb[j] + k0);
        #pragma unroll
        for (int i = 0; i < 4; ++i)
            #pragma unroll
            for (int j = 0; j < 4; ++j)
                acc[i][j] = __builtin_amdgcn_mfma_f32_16x16x32_bf16(fa[i], fb[j], acc[i][j], 0, 0, 0);
    }
    #pragma unroll 2
    for (int k0 = 0; k0 < KHALF; k0 += 32) {
        bf16x8 fa[4], fb[4];
        #pragma unroll
        for (int i = 0; i < 4; ++i) fa[i] = *(const bf16x8*)(pa2[i] + k0);
        #pragma unroll
        for (int j = 0; j < 4; ++j) fb[j] = *(const bf16x8*)(pb[j] + KHALF + k0);
        #pragma unroll
        for (int i = 0; i < 4; ++i)
            #pragma unroll
            for (int j = 0; j < 4; ++j)
                acc[i][j] = __builtin_amdgcn_mfma_f32_16x16x32_bf16(fa[i], fb[j], acc[i][j], 0, 0, 0);
    }

    // C/D layout: col = lane&15, row = (lane>>4)*4 + reg
    #pragma unroll
    for (int j = 0; j < 4; ++j) {
        const int colg = col0 + j * 16 + lr;
        const float bj = bias[colg];
        #pragma unroll
        for (int i = 0; i < 4; ++i) {
            #pragma unroll
            for (int reg = 0; reg < 4; ++reg) {
                const int rowg = row0 + i * 16 + (l >> 4) * 4 + reg;
                if (rowg < Mrows) {
                    float v = acc[i][j][reg] + bj;
                    if (RELU) v = fmaxf(v, 0.f);
                    if (OUTBF16) outb[(size_t)rowg * LDC + colg] = (__bf16)v;
                    else         outf[(size_t)rowg * LDC + colg] = v;
                }
            }
        }
    }
}

// ---------------- launch ----------------

extern "C" void kernel_launch(void* const* d_in, const int* in_sizes, int n_in,
                              void* d_out, int out_size, void* d_ws, size_t ws_size,
                              hipStream_t stream) {
    const float* x   = (const float*)d_in[0];
    const float* Wl0 = (const float*)d_in[1];
    const float* bl0 = (const float*)d_in[2];
    const float* Wr0 = (const float*)d_in[3];
    const float* Wl1 = (const float*)d_in[4];
    const float* bl1 = (const float*)d_in[5];
    const float* Wr1 = (const float*)d_in[6];
    const int* e0s = (const int*)d_in[7];
    const int* e0d = (const int*)d_in[8];
    const int* e1s = (const int*)d_in[9];
    const int* e1d = (const int*)d_in[10];
    float* out = (float*)d_out;

    char* ws = (char*)d_ws;
    size_t pos = 0;
    auto alloc = [&](size_t nb) -> void* {
        void* p = ws + pos;
        pos += (nb + 255) & ~(size_t)255;
        return p;
    };
    __bf16* xb   = (__bf16*)alloc((size_t)cN0 * 128 * 2);   // 128 MB [cast .. gemm0]
    __bf16* h    = (__bf16*)alloc((size_t)cN1 * 256 * 2);   // 51.2 MB [gemm0 .. gemm1]
    __bf16* Agg0 = (__bf16*)alloc((size_t)cN1 * 128 * 2);   // 25.6 MB [agg0 .. gemm0]
    __bf16* Agg1 = Agg0;                                    // aliases Agg0 (dead by then)
    int* off0    = (int*)alloc((size_t)(cN1 + 1) * 4);
    int* cur0    = (int*)alloc((size_t)cN1 * 4);
    int* srcs0   = (int*)alloc((size_t)cE0 * 4);
    int* off1    = (int*)alloc((size_t)(cN2 + 1) * 4);
    int* cur1    = (int*)alloc((size_t)cN2 * 4);
    int* srcs1   = (int*)alloc((size_t)cE1 * 4);
    int* bsum    = (int*)alloc(128 * 4);
    __bf16* Wc0  = (__bf16*)alloc(256 * 256 * 2);
    __bf16* Wc1  = (__bf16*)alloc(128 * 512 * 2);
    __bf16* zrow = (__bf16*)alloc(256 * 2);
    (void)ws_size; (void)in_sizes; (void)n_in; (void)out_size;

    // --- init + cast ---
    hipMemsetAsync(off0, 0, (size_t)(cN1 + 1) * 4, stream);
    hipMemsetAsync(off1, 0, (size_t)(cN2 + 1) * 4, stream);
    hipMemsetAsync(zrow, 0, 256 * 2, stream);
    k_cast<<<(cN0 * 128 / 8 + 255) / 256, 256, 0, stream>>>(x, xb, cN0 * 128 / 8);

    // --- CSR build ---
    k_hist<<<(cE0 + 255) / 256, 256, 0, stream>>>(e0d, cE0, off0);
    k_hist<<<(cE1 + 255) / 256, 256, 0, stream>>>(e1d, cE1, off1);

    const int nb0 = (cN1 + 1023) / 1024;
    k_scan1<<<nb0, 256, 0, stream>>>(off0, cN1, bsum);
    k_scan2<<<1, 128, 0, stream>>>(bsum, nb0);
    k_scan3<<<(cN1 + 255) / 256, 256, 0, stream>>>(off0, cN1, bsum, cE0, cur0);
    k_scatter<<<(cE0 + 255) / 256, 256, 0, stream>>>(e0s, e0d, cE0, cur0, srcs0);

    const int nb1 = (cN2 + 1023) / 1024;
    k_scan1<<<nb1, 256, 0, stream>>>(off1, cN2, bsum);
    k_scan2<<<1, 128, 0, stream>>>(bsum, nb1);
    k_scan3<<<(cN2 + 255) / 256, 256, 0, stream>>>(off1, cN2, bsum, cE1, cur1);
    k_scatter<<<(cE1 + 255) / 256, 256, 0, stream>>>(e1s, e1d, cE1, cur1, srcs1);

    // --- weights to bf16 concat ---
    k_wcat0<<<(256 * 256 + 255) / 256, 256, 0, stream>>>(Wl0, Wr0, Wc0);
    k_wcat1<<<(128 * 512 + 255) / 256, 256, 0, stream>>>(Wl1, Wr1, Wc1);

    // --- hop 0 ---
    k_agg0<<<(cN1 + 31) / 32, 256, 0, stream>>>(xb, off0, srcs0, zrow, Agg0);
    {
        dim3 grid((cN1 + 127) / 128, 2);
        k_gemm<128, 256, true, true><<<grid, 256, 0, stream>>>(Agg0, xb, Wc0, bl0, nullptr, h, cN1);
    }
    // --- hop 1 ---
    k_agg1<<<(cN2 + 15) / 16, 256, 0, stream>>>(h, off1, srcs1, zrow, Agg1);
    {
        dim3 grid((cN2 + 127) / 128, 1);
        k_gemm<256, 128, false, false><<<grid, 256, 0, stream>>>(Agg1, h, Wc1, bl1, out, nullptr, cN2);
    }
}

// Round 4
// 850.502 us; speedup vs baseline: 1.0340x; 1.0340x over previous
//
#include <hip/hip_runtime.h>
#include <hip/hip_bf16.h>

#define cN0 500000
#define cN1 100000
#define cN2 25000
#define cE0 1600000
#define cE1 400000

typedef __bf16 bf16x8 __attribute__((ext_vector_type(8)));
typedef __bf16 bf16x4 __attribute__((ext_vector_type(4)));
typedef float f32x4 __attribute__((ext_vector_type(4)));

// ---------------- fused prep: cast | hist0 | hist1 | wcat0 | wcat1 ----------------
// block ranges (256 thr each):
//   [0, 31250)        cast: xb = bf16(x), 8,000,000 x8-groups
//   [31250, 37500)    hist0: 1,600,000 edges
//   [37500, 39063)    hist1: 400,000 edges
//   [39063, 39319)    wcat0: 65,536 elems
//   [39319, 39575)    wcat1: 65,536 elems
__global__ __launch_bounds__(256) void k_prep(
    const float* __restrict__ x, __bf16* __restrict__ xb,
    const int* __restrict__ e0d, int* __restrict__ off0,
    const int* __restrict__ e1d, int* __restrict__ off1,
    const float* __restrict__ Wl0, const float* __restrict__ Wr0, __bf16* __restrict__ Wc0,
    const float* __restrict__ Wl1, const float* __restrict__ Wr1, __bf16* __restrict__ Wc1)
{
    const int b = blockIdx.x;
    const int t = threadIdx.x;
    if (b < 31250) {
        const int i = b * 256 + t;                 // exactly 8,000,000
        const float4 v0 = *(const float4*)(x + (size_t)i * 8);
        const float4 v1 = *(const float4*)(x + (size_t)i * 8 + 4);
        bf16x8 o;
        o[0] = (__bf16)v0.x; o[1] = (__bf16)v0.y; o[2] = (__bf16)v0.z; o[3] = (__bf16)v0.w;
        o[4] = (__bf16)v1.x; o[5] = (__bf16)v1.y; o[6] = (__bf16)v1.z; o[7] = (__bf16)v1.w;
        *(bf16x8*)(xb + (size_t)i * 8) = o;
    } else if (b < 37500) {
        const int i = (b - 31250) * 256 + t;       // exactly 1,600,000
        atomicAdd(&off0[e0d[i]], 1);
    } else if (b < 39063) {
        const int i = (b - 37500) * 256 + t;
        if (i < cE1) atomicAdd(&off1[e1d[i]], 1);
    } else if (b < 39319) {
        const int i = (b - 39063) * 256 + t;       // 256*256
        const int j = i >> 8, k = i & 255;
        float v = (k < 128) ? Wl0[j * 128 + k] : Wr0[j * 128 + (k - 128)];
        Wc0[i] = (__bf16)v;
    } else {
        const int i = (b - 39319) * 256 + t;       // 128*512
        const int j = i >> 9, k = i & 511;
        float v = (k < 256) ? Wl1[j * 256 + k] : Wr1[j * 256 + (k - 256)];
        Wc1[i] = (__bf16)v;
    }
}

// ---------------- fused scans (both hops) ----------------
// scanA: blocks [0,98) -> off0 (n=cN1), blocks [98,123) -> off1 (n=cN2)
__global__ void k_scanA(int* __restrict__ off0, int* __restrict__ bsum0,
                        int* __restrict__ off1, int* __restrict__ bsum1) {
    __shared__ int lds[256];
    const int t = threadIdx.x;
    int* a; int n; int* bsum; int blk;
    if (blockIdx.x < 98) { a = off0; n = cN1; bsum = bsum0; blk = blockIdx.x; }
    else                 { a = off1; n = cN2; bsum = bsum1; blk = blockIdx.x - 98; }
    const int base = blk * 1024 + t * 4;
    int v0 = (base + 0 < n) ? a[base + 0] : 0;
    int v1 = (base + 1 < n) ? a[base + 1] : 0;
    int v2 = (base + 2 < n) ? a[base + 2] : 0;
    int v3 = (base + 3 < n) ? a[base + 3] : 0;
    const int s = v0 + v1 + v2 + v3;
    lds[t] = s;
    __syncthreads();
    int x = s;
    for (int d = 1; d < 256; d <<= 1) {
        int y = (t >= d) ? lds[t - d] : 0;
        __syncthreads();
        x += y;
        lds[t] = x;
        __syncthreads();
    }
    if (t == 255) bsum[blk] = x;
    int e0 = x - s;
    int e1 = e0 + v0, e2 = e1 + v1, e3 = e2 + v2;
    if (base + 0 < n) a[base + 0] = e0;
    if (base + 1 < n) a[base + 1] = e1;
    if (base + 2 < n) a[base + 2] = e2;
    if (base + 3 < n) a[base + 3] = e3;
}

// scanB: block 0 -> bsum0 (nb=98), block 1 -> bsum1 (nb=25)
__global__ void k_scanB(int* __restrict__ bsum0, int* __restrict__ bsum1) {
    __shared__ int lds[128];
    const int t = threadIdx.x;
    int* bsum = (blockIdx.x == 0) ? bsum0 : bsum1;
    const int nb = (blockIdx.x == 0) ? 98 : 25;
    int v = (t < nb) ? bsum[t] : 0;
    lds[t] = v;
    __syncthreads();
    int x = v;
    for (int d = 1; d < 128; d <<= 1) {
        int y = (t >= d) ? lds[t - d] : 0;
        __syncthreads();
        x += y;
        lds[t] = x;
        __syncthreads();
    }
    if (t < nb) bsum[t] = x - v;
}

// scanC: blocks [0,391) -> hop0, [391,489) -> hop1 ; adds offsets + copies cursor
__global__ void k_scanC(int* __restrict__ off0, const int* __restrict__ bsum0, int* __restrict__ cur0,
                        int* __restrict__ off1, const int* __restrict__ bsum1, int* __restrict__ cur1) {
    int* a; const int* bsum; int* cur; int n, total, blk;
    if (blockIdx.x < 391) { a = off0; bsum = bsum0; cur = cur0; n = cN1; total = cE0; blk = blockIdx.x; }
    else                  { a = off1; bsum = bsum1; cur = cur1; n = cN2; total = cE1; blk = blockIdx.x - 391; }
    const int i = blk * 256 + threadIdx.x;
    if (i < n) {
        int v = a[i] + bsum[i >> 10];
        a[i] = v;
        cur[i] = v;
    }
    if (i == 0) a[n] = total;
}

// scatter both hops: blocks [0,6250) -> hop0, [6250,7813) -> hop1
__global__ void k_scatter2(const int* __restrict__ e0s, const int* __restrict__ e0d,
                           int* __restrict__ cur0, int* __restrict__ srcs0,
                           const int* __restrict__ e1s, const int* __restrict__ e1d,
                           int* __restrict__ cur1, int* __restrict__ srcs1) {
    if (blockIdx.x < 6250) {
        const int i = blockIdx.x * 256 + threadIdx.x;     // exactly 1,600,000
        const int p = atomicAdd(&cur0[e0d[i]], 1);
        srcs0[p] = e0s[i];
    } else {
        const int i = (blockIdx.x - 6250) * 256 + threadIdx.x;
        if (i < cE1) {
            const int p = atomicAdd(&cur1[e1d[i]], 1);
            srcs1[p] = e1s[i];
        }
    }
}

// ---------------- hop0 aggregation: Agg0[g] = bf16(mean xb_src) ----------------
// wave = 4 edge-slots x 16 dim-lanes (16B bf16x8/lane); 8 nodes per wave.
__global__ __launch_bounds__(256) void k_agg0(
    const __bf16* __restrict__ xb,
    const int* __restrict__ off, const int* __restrict__ srcs,
    const __bf16* __restrict__ zrow,
    __bf16* __restrict__ Agg)
{
    const int wid = blockIdx.x * 4 + (threadIdx.x >> 6);
    const int lane = threadIdx.x & 63;
    const int slot = lane >> 4;          // 0..3
    const int dl = lane & 15;            // dims dl*8 .. dl*8+7
    const int gbase = wid * 8;
    for (int n = 0; n < 8; ++n) {
        const int g = gbase + n;
        if (g >= cN1) return;
        const int e0 = off[g], e1 = off[g + 1];
        const int deg = e1 - e0;
        float a[8] = {0.f, 0.f, 0.f, 0.f, 0.f, 0.f, 0.f, 0.f};
        const int iters = (deg + 3) >> 2;
        for (int it = 0; it < iters; ++it) {
            const int e = e0 + it * 4 + slot;
            const __bf16* rp = zrow;
            if (e < e1) rp = xb + (size_t)srcs[e] * 128;
            const bf16x8 r = *(const bf16x8*)(rp + dl * 8);
            #pragma unroll
            for (int d = 0; d < 8; ++d) a[d] += (float)r[d];
        }
        #pragma unroll
        for (int d = 0; d < 8; ++d) {
            a[d] += __shfl_xor(a[d], 16);
            a[d] += __shfl_xor(a[d], 32);
        }
        if (slot == 0) {
            const float inv = 1.f / (float)(deg > 0 ? deg : 1);
            bf16x8 o;
            #pragma unroll
            for (int d = 0; d < 8; ++d) o[d] = (__bf16)(a[d] * inv);
            *(bf16x8*)(Agg + (size_t)g * 128 + dl * 8) = o;
        }
    }
}

// ---------------- hop1 aggregation: Agg1[g] = bf16(mean h_src) ----------------
__global__ __launch_bounds__(256) void k_agg1(
    const __bf16* __restrict__ h,
    const int* __restrict__ off, const int* __restrict__ srcs,
    const __bf16* __restrict__ zrow,
    __bf16* __restrict__ Agg)
{
    const int wid = blockIdx.x * 4 + (threadIdx.x >> 6);
    const int lane = threadIdx.x & 63;
    const int slot = lane >> 5;          // 0..1
    const int dl = lane & 31;            // dims dl*8 .. dl*8+7
    const int gbase = wid * 4;
    for (int n = 0; n < 4; ++n) {
        const int g = gbase + n;
        if (g >= cN2) return;
        const int e0 = off[g], e1 = off[g + 1];
        const int deg = e1 - e0;
        float a[8] = {0.f, 0.f, 0.f, 0.f, 0.f, 0.f, 0.f, 0.f};
        const int iters = (deg + 1) >> 1;
        for (int it = 0; it < iters; ++it) {
            const int e = e0 + it * 2 + slot;
            const __bf16* rp = zrow;
            if (e < e1) rp = h + (size_t)srcs[e] * 256;
            const bf16x8 r = *(const bf16x8*)(rp + dl * 8);
            #pragma unroll
            for (int d = 0; d < 8; ++d) a[d] += (float)r[d];
        }
        #pragma unroll
        for (int d = 0; d < 8; ++d) a[d] += __shfl_xor(a[d], 32);
        if (slot == 0) {
            const float inv = 1.f / (float)(deg > 0 ? deg : 1);
            bf16x8 o;
            #pragma unroll
            for (int d = 0; d < 8; ++d) o[d] = (__bf16)(a[d] * inv);
            *(bf16x8*)(Agg + (size_t)g * 256 + dl * 8) = o;
        }
    }
}

// ---------------- bf16 MFMA GEMM: C = act([A1|A2] @ W^T + bias) ----------------
template<int KHALF, int LDC, bool RELU, bool OUTBF16>
__global__ __launch_bounds__(256) void k_gemm(
    const __bf16* __restrict__ A1, const __bf16* __restrict__ A2,
    const __bf16* __restrict__ W, const float* __restrict__ bias,
    float* __restrict__ outf, __bf16* __restrict__ outb, int Mrows)
{
    const int K = KHALF * 2;
    const int tid = threadIdx.x;
    const int l = tid & 63;
    const int w = tid >> 6;
    const int wm = w & 1, wn = w >> 1;
    const int row0 = blockIdx.x * 128 + wm * 64;
    const int col0 = blockIdx.y * 128 + wn * 64;
    const int lr = l & 15;
    const int lk = (l >> 4) * 8;

    const __bf16* pa1[4];
    const __bf16* pa2[4];
    const __bf16* pb[4];
    #pragma unroll
    for (int i = 0; i < 4; ++i) {
        int r = row0 + i * 16 + lr;
        r = (r < Mrows) ? r : (Mrows - 1);
        pa1[i] = A1 + (size_t)r * KHALF + lk;
        pa2[i] = A2 + (size_t)r * KHALF + lk;
        pb[i] = W + (size_t)(col0 + i * 16 + lr) * K + lk;
    }
    f32x4 acc[4][4];
    #pragma unroll
    for (int i = 0; i < 4; ++i)
        #pragma unroll
        for (int j = 0; j < 4; ++j)
            acc[i][j] = (f32x4)0.0f;

    #pragma unroll 2
    for (int k0 = 0; k0 < KHALF; k0 += 32) {
        bf16x8 fa[4], fb[4];
        #pragma unroll
        for (int i = 0; i < 4; ++i) fa[i] = *(const bf16x8*)(pa1[i] + k0);
        #pragma unroll
        for (int j = 0; j < 4; ++j) fb[j] = *(const bf16x8*)(pb[j] + k0);
        #pragma unroll
        for (int i = 0; i < 4; ++i)
            #pragma unroll
            for (int j = 0; j < 4; ++j)
                acc[i][j] = __builtin_amdgcn_mfma_f32_16x16x32_bf16(fa[i], fb[j], acc[i][j], 0, 0, 0);
    }
    #pragma unroll 2
    for (int k0 = 0; k0 < KHALF; k0 += 32) {
        bf16x8 fa[4], fb[4];
        #pragma unroll
        for (int i = 0; i < 4; ++i) fa[i] = *(const bf16x8*)(pa2[i] + k0);
        #pragma unroll
        for (int j = 0; j < 4; ++j) fb[j] = *(const bf16x8*)(pb[j] + KHALF + k0);
        #pragma unroll
        for (int i = 0; i < 4; ++i)
            #pragma unroll
            for (int j = 0; j < 4; ++j)
                acc[i][j] = __builtin_amdgcn_mfma_f32_16x16x32_bf16(fa[i], fb[j], acc[i][j], 0, 0, 0);
    }

    // C/D layout: col = lane&15, row = (lane>>4)*4 + reg
    #pragma unroll
    for (int j = 0; j < 4; ++j) {
        const int colg = col0 + j * 16 + lr;
        const float bj = bias[colg];
        #pragma unroll
        for (int i = 0; i < 4; ++i) {
            #pragma unroll
            for (int reg = 0; reg < 4; ++reg) {
                const int rowg = row0 + i * 16 + (l >> 4) * 4 + reg;
                if (rowg < Mrows) {
                    float v = acc[i][j][reg] + bj;
                    if (RELU) v = fmaxf(v, 0.f);
                    if (OUTBF16) outb[(size_t)rowg * LDC + colg] = (__bf16)v;
                    else         outf[(size_t)rowg * LDC + colg] = v;
                }
            }
        }
    }
}

// ---------------- launch ----------------

extern "C" void kernel_launch(void* const* d_in, const int* in_sizes, int n_in,
                              void* d_out, int out_size, void* d_ws, size_t ws_size,
                              hipStream_t stream) {
    const float* x   = (const float*)d_in[0];
    const float* Wl0 = (const float*)d_in[1];
    const float* bl0 = (const float*)d_in[2];
    const float* Wr0 = (const float*)d_in[3];
    const float* Wl1 = (const float*)d_in[4];
    const float* bl1 = (const float*)d_in[5];
    const float* Wr1 = (const float*)d_in[6];
    const int* e0s = (const int*)d_in[7];
    const int* e0d = (const int*)d_in[8];
    const int* e1s = (const int*)d_in[9];
    const int* e1d = (const int*)d_in[10];
    float* out = (float*)d_out;

    char* ws = (char*)d_ws;
    size_t pos = 0;
    auto alloc = [&](size_t nb) -> void* {
        void* p = ws + pos;
        pos += (nb + 255) & ~(size_t)255;
        return p;
    };
    __bf16* xb   = (__bf16*)alloc((size_t)cN0 * 128 * 2);   // 128 MB
    __bf16* h    = (__bf16*)alloc((size_t)cN1 * 256 * 2);   // 51.2 MB
    __bf16* Agg0 = (__bf16*)alloc((size_t)cN1 * 128 * 2);   // 25.6 MB
    __bf16* Agg1 = Agg0;                                    // aliases Agg0
    // contiguous zero-init strip: off0 | off1 | zrow (single memset)
    int* off0    = (int*)alloc(((size_t)(cN1 + 1) + (cN2 + 1) + 128) * 4);
    int* off1    = off0 + (cN1 + 1);
    __bf16* zrow = (__bf16*)(off1 + (cN2 + 1));
    const size_t zbytes = ((size_t)(cN1 + 1) + (cN2 + 1) + 128) * 4;
    int* cur0    = (int*)alloc((size_t)cN1 * 4);
    int* srcs0   = (int*)alloc((size_t)cE0 * 4);
    int* cur1    = (int*)alloc((size_t)cN2 * 4);
    int* srcs1   = (int*)alloc((size_t)cE1 * 4);
    int* bsum0   = (int*)alloc(128 * 4);
    int* bsum1   = (int*)alloc(128 * 4);
    __bf16* Wc0  = (__bf16*)alloc(256 * 256 * 2);
    __bf16* Wc1  = (__bf16*)alloc(128 * 512 * 2);
    (void)ws_size; (void)in_sizes; (void)n_in; (void)out_size;

    // 1. zero strip
    hipMemsetAsync(off0, 0, zbytes, stream);
    // 2. fused prep: cast + hist0 + hist1 + wcat0 + wcat1
    k_prep<<<39575, 256, 0, stream>>>(x, xb, e0d, off0, e1d, off1,
                                      Wl0, Wr0, Wc0, Wl1, Wr1, Wc1);
    // 3-5. scans (both hops per launch)
    k_scanA<<<123, 256, 0, stream>>>(off0, bsum0, off1, bsum1);
    k_scanB<<<2, 128, 0, stream>>>(bsum0, bsum1);
    k_scanC<<<489, 256, 0, stream>>>(off0, bsum0, cur0, off1, bsum1, cur1);
    // 6. scatter (both hops)
    k_scatter2<<<7813, 256, 0, stream>>>(e0s, e0d, cur0, srcs0, e1s, e1d, cur1, srcs1);

    // 7-8. hop 0
    k_agg0<<<(cN1 + 31) / 32, 256, 0, stream>>>(xb, off0, srcs0, zrow, Agg0);
    {
        dim3 grid((cN1 + 127) / 128, 2);
        k_gemm<128, 256, true, true><<<grid, 256, 0, stream>>>(Agg0, xb, Wc0, bl0, nullptr, h, cN1);
    }
    // 9-10. hop 1
    k_agg1<<<(cN2 + 15) / 16, 256, 0, stream>>>(h, off1, srcs1, zrow, Agg1);
    {
        dim3 grid((cN2 + 127) / 128, 1);
        k_gemm<256, 128, false, false><<<grid, 256, 0, stream>>>(Agg1, h, Wc1, bl1, out, nullptr, cN2);
    }
}

// Round 5
// 836.922 us; speedup vs baseline: 1.0508x; 1.0162x over previous
//
#include <hip/hip_runtime.h>
#include <hip/hip_bf16.h>

#define cN0 500000
#define cN1 100000
#define cN2 25000
#define cE0 1600000
#define cE1 400000
#define NB0 6250     // cN1/16 buckets (exact)
#define NB1 1563     // ceil(cN2/16)

typedef __bf16 bf16x8 __attribute__((ext_vector_type(8)));
typedef float f32x4 __attribute__((ext_vector_type(4)));

// ---------------- fused prep: cast | bucket-hist0 | bucket-hist1 | wcat0 | wcat1 ----------------
// block ranges (256 thr each):
//   [0, 31250)        cast: xb = bf16(x), 8,000,000 x8-groups
//   [31250, 37500)    bkt0 hist: 1,600,000 edges -> 6250 counters
//   [37500, 39063)    bkt1 hist: 400,000 edges -> 1563 counters
//   [39063, 39319)    wcat0
//   [39319, 39575)    wcat1
__global__ __launch_bounds__(256) void k_prep(
    const float* __restrict__ x, __bf16* __restrict__ xb,
    const int* __restrict__ e0d, int* __restrict__ bkt0,
    const int* __restrict__ e1d, int* __restrict__ bkt1,
    const float* __restrict__ Wl0, const float* __restrict__ Wr0, __bf16* __restrict__ Wc0,
    const float* __restrict__ Wl1, const float* __restrict__ Wr1, __bf16* __restrict__ Wc1)
{
    const int b = blockIdx.x;
    const int t = threadIdx.x;
    if (b < 31250) {
        const int i = b * 256 + t;
        const float4 v0 = *(const float4*)(x + (size_t)i * 8);
        const float4 v1 = *(const float4*)(x + (size_t)i * 8 + 4);
        bf16x8 o;
        o[0] = (__bf16)v0.x; o[1] = (__bf16)v0.y; o[2] = (__bf16)v0.z; o[3] = (__bf16)v0.w;
        o[4] = (__bf16)v1.x; o[5] = (__bf16)v1.y; o[6] = (__bf16)v1.z; o[7] = (__bf16)v1.w;
        *(bf16x8*)(xb + (size_t)i * 8) = o;
    } else if (b < 37500) {
        const int i = (b - 31250) * 256 + t;       // exactly 1,600,000
        atomicAdd(&bkt0[e0d[i] >> 4], 1);
    } else if (b < 39063) {
        const int i = (b - 37500) * 256 + t;
        if (i < cE1) atomicAdd(&bkt1[e1d[i] >> 4], 1);
    } else if (b < 39319) {
        const int i = (b - 39063) * 256 + t;       // 256*256
        const int j = i >> 8, k = i & 255;
        float v = (k < 128) ? Wl0[j * 128 + k] : Wr0[j * 128 + (k - 128)];
        Wc0[i] = (__bf16)v;
    } else {
        const int i = (b - 39319) * 256 + t;       // 128*512
        const int j = i >> 9, k = i & 511;
        float v = (k < 256) ? Wl1[j * 256 + k] : Wr1[j * 256 + (k - 256)];
        Wc1[i] = (__bf16)v;
    }
}

// ---------------- bucket-count scans ----------------
// scanA: blocks [0,7) -> bkt0 (n=NB0), blocks [7,9) -> bkt1 (n=NB1)
__global__ void k_scanA(int* __restrict__ bkt0, int* __restrict__ bsum0,
                        int* __restrict__ bkt1, int* __restrict__ bsum1) {
    __shared__ int lds[256];
    const int t = threadIdx.x;
    int* a; int n; int* bsum; int blk;
    if (blockIdx.x < 7) { a = bkt0; n = NB0; bsum = bsum0; blk = blockIdx.x; }
    else                { a = bkt1; n = NB1; bsum = bsum1; blk = blockIdx.x - 7; }
    const int base = blk * 1024 + t * 4;
    int v0 = (base + 0 < n) ? a[base + 0] : 0;
    int v1 = (base + 1 < n) ? a[base + 1] : 0;
    int v2 = (base + 2 < n) ? a[base + 2] : 0;
    int v3 = (base + 3 < n) ? a[base + 3] : 0;
    const int s = v0 + v1 + v2 + v3;
    lds[t] = s;
    __syncthreads();
    int x = s;
    for (int d = 1; d < 256; d <<= 1) {
        int y = (t >= d) ? lds[t - d] : 0;
        __syncthreads();
        x += y;
        lds[t] = x;
        __syncthreads();
    }
    if (t == 255) bsum[blk] = x;
    int e0 = x - s;
    int e1 = e0 + v0, e2 = e1 + v1, e3 = e2 + v2;
    if (base + 0 < n) a[base + 0] = e0;
    if (base + 1 < n) a[base + 1] = e1;
    if (base + 2 < n) a[base + 2] = e2;
    if (base + 3 < n) a[base + 3] = e3;
}

// scanB: block 0 -> bsum0 (nb=7), block 1 -> bsum1 (nb=2)
__global__ void k_scanB(int* __restrict__ bsum0, int* __restrict__ bsum1) {
    __shared__ int lds[128];
    const int t = threadIdx.x;
    int* bsum = (blockIdx.x == 0) ? bsum0 : bsum1;
    const int nb = (blockIdx.x == 0) ? 7 : 2;
    int v = (t < nb) ? bsum[t] : 0;
    lds[t] = v;
    __syncthreads();
    int x = v;
    for (int d = 1; d < 128; d <<= 1) {
        int y = (t >= d) ? lds[t - d] : 0;
        __syncthreads();
        x += y;
        lds[t] = x;
        __syncthreads();
    }
    if (t < nb) bsum[t] = x - v;
}

// scanC: blocks [0,25) -> bkt0 (+cursor copy), [25,32) -> bkt1
__global__ void k_scanC(int* __restrict__ bkt0, const int* __restrict__ bsum0, int* __restrict__ bcur0,
                        int* __restrict__ bkt1, const int* __restrict__ bsum1, int* __restrict__ bcur1) {
    int* a; const int* bsum; int* cur; int n, total, blk;
    if (blockIdx.x < 25) { a = bkt0; bsum = bsum0; cur = bcur0; n = NB0; total = cE0; blk = blockIdx.x; }
    else                 { a = bkt1; bsum = bsum1; cur = bcur1; n = NB1; total = cE1; blk = blockIdx.x - 25; }
    const int i = blk * 256 + threadIdx.x;
    if (i < n) {
        int v = a[i] + bsum[i >> 10];
        a[i] = v;
        cur[i] = v;
    }
    if (i == 0) a[n] = total;
}

// ---------------- phase B: scatter (src,dst) pairs into bucket-contiguous spans ----------------
// blocks [0,6250) -> hop0, [6250,7813) -> hop1
__global__ void k_phaseB(const int* __restrict__ e0s, const int* __restrict__ e0d,
                         int* __restrict__ bcur0, int2* __restrict__ pair0,
                         const int* __restrict__ e1s, const int* __restrict__ e1d,
                         int* __restrict__ bcur1, int2* __restrict__ pair1) {
    if (blockIdx.x < 6250) {
        const int i = blockIdx.x * 256 + threadIdx.x;    // exactly 1,600,000
        const int d = e0d[i];
        const int p = atomicAdd(&bcur0[d >> 4], 1);
        pair0[p] = make_int2(e0s[i], d);
    } else {
        const int i = (blockIdx.x - 6250) * 256 + threadIdx.x;
        if (i < cE1) {
            const int d = e1d[i];
            const int p = atomicAdd(&bcur1[d >> 4], 1);
            pair1[p] = make_int2(e1s[i], d);
        }
    }
}

// ---------------- phase C: per-bucket CSR build (LDS atomics only) ----------------
// blocks [0,NB0) -> hop0, [NB0, NB0+NB1) -> hop1. Writes off[] and srcs[].
__global__ __launch_bounds__(256) void k_phaseC(
    const int* __restrict__ boff0, const int2* __restrict__ pair0,
    int* __restrict__ off0, int* __restrict__ srcs0,
    const int* __restrict__ boff1, const int2* __restrict__ pair1,
    int* __restrict__ off1, int* __restrict__ srcs1) {
    __shared__ int deg[16], pre[16], cur[16];
    const int t = threadIdx.x;
    const int* boff; const int2* pr; int* off; int* srcs; int bkt, ndst, Etot;
    if (blockIdx.x < NB0) { bkt = blockIdx.x;       boff = boff0; pr = pair0; off = off0; srcs = srcs0; ndst = cN1; Etot = cE0; }
    else                  { bkt = blockIdx.x - NB0; boff = boff1; pr = pair1; off = off1; srcs = srcs1; ndst = cN2; Etot = cE1; }
    const int p0 = boff[bkt], p1 = boff[bkt + 1];
    const int cnt = p1 - p0;
    if (t < 16) deg[t] = 0;
    __syncthreads();
    for (int i = t; i < cnt; i += 256) atomicAdd(&deg[pr[p0 + i].y & 15], 1);
    __syncthreads();
    if (t == 0) {
        int s = 0;
        #pragma unroll
        for (int l = 0; l < 16; ++l) { pre[l] = s; cur[l] = s; s += deg[l]; }
    }
    __syncthreads();
    if (t < 16) {
        const int d = bkt * 16 + t;
        if (d < ndst) off[d] = p0 + pre[t];
    }
    if (t == 0 && bkt == 0) off[ndst] = Etot;
    for (int i = t; i < cnt; i += 256) {
        const int2 e = pr[p0 + i];
        const int p = atomicAdd(&cur[e.y & 15], 1);
        srcs[p0 + p] = e.x;
    }
}

// ---------------- hop0 aggregation: Agg0[g] = bf16(mean xb_src), 2-node interleave ----------------
// wave = 4 edge-slots x 16 dim-lanes; 8 nodes/wave (4 pairs). 12500 waves exact.
__global__ __launch_bounds__(256) void k_agg0(
    const __bf16* __restrict__ xb,
    const int* __restrict__ off, const int* __restrict__ srcs,
    const __bf16* __restrict__ zrow,
    __bf16* __restrict__ Agg)
{
    const int wid = blockIdx.x * 4 + (threadIdx.x >> 6);
    const int lane = threadIdx.x & 63;
    const int slot = lane >> 4;          // 0..3
    const int dl = lane & 15;            // dims dl*8 .. dl*8+7
    const int gbase = wid * 8;
    for (int n = 0; n < 8; n += 2) {
        const int ga = gbase + n, gb = gbase + n + 1;
        const int a0 = off[ga], a1 = off[ga + 1];
        const int b0 = off[gb], b1 = off[gb + 1];
        float aa[8] = {0.f,0.f,0.f,0.f,0.f,0.f,0.f,0.f};
        float ab[8] = {0.f,0.f,0.f,0.f,0.f,0.f,0.f,0.f};
        const int ita = (a1 - a0 + 3) >> 2;
        const int itb = (b1 - b0 + 3) >> 2;
        const int it = (ita > itb) ? ita : itb;
        for (int i2 = 0; i2 < it; ++i2) {
            const int ea = a0 + i2 * 4 + slot;
            const int eb = b0 + i2 * 4 + slot;
            const __bf16* pa = (ea < a1) ? xb + (size_t)srcs[ea] * 128 : zrow;
            const __bf16* pb = (eb < b1) ? xb + (size_t)srcs[eb] * 128 : zrow;
            const bf16x8 ra = *(const bf16x8*)(pa + dl * 8);
            const bf16x8 rb = *(const bf16x8*)(pb + dl * 8);
            #pragma unroll
            for (int d = 0; d < 8; ++d) { aa[d] += (float)ra[d]; ab[d] += (float)rb[d]; }
        }
        #pragma unroll
        for (int d = 0; d < 8; ++d) {
            aa[d] += __shfl_xor(aa[d], 16);
            aa[d] += __shfl_xor(aa[d], 32);
            ab[d] += __shfl_xor(ab[d], 16);
            ab[d] += __shfl_xor(ab[d], 32);
        }
        if (slot == 0) {
            const int deg = a1 - a0;
            const float inv = 1.f / (float)(deg > 0 ? deg : 1);
            bf16x8 o;
            #pragma unroll
            for (int d = 0; d < 8; ++d) o[d] = (__bf16)(aa[d] * inv);
            *(bf16x8*)(Agg + (size_t)ga * 128 + dl * 8) = o;
        } else if (slot == 1) {
            const int deg = b1 - b0;
            const float inv = 1.f / (float)(deg > 0 ? deg : 1);
            bf16x8 o;
            #pragma unroll
            for (int d = 0; d < 8; ++d) o[d] = (__bf16)(ab[d] * inv);
            *(bf16x8*)(Agg + (size_t)gb * 128 + dl * 8) = o;
        }
    }
}

// ---------------- hop1 aggregation: Agg1[g] = bf16(mean h_src), 2-node interleave ----------------
// wave = 2 edge-slots x 32 dim-lanes; 4 nodes/wave (2 pairs).
__global__ __launch_bounds__(256) void k_agg1(
    const __bf16* __restrict__ h,
    const int* __restrict__ off, const int* __restrict__ srcs,
    const __bf16* __restrict__ zrow,
    __bf16* __restrict__ Agg)
{
    const int wid = blockIdx.x * 4 + (threadIdx.x >> 6);
    const int lane = threadIdx.x & 63;
    const int slot = lane >> 5;          // 0..1
    const int dl = lane & 31;            // dims dl*8 .. dl*8+7
    const int gbase = wid * 4;
    if (gbase >= cN2) return;
    for (int n = 0; n < 4; n += 2) {
        const int ga = gbase + n, gb = gbase + n + 1;
        const int a0 = off[ga], a1 = off[ga + 1];
        const int b0 = off[gb], b1 = off[gb + 1];
        float aa[8] = {0.f,0.f,0.f,0.f,0.f,0.f,0.f,0.f};
        float ab[8] = {0.f,0.f,0.f,0.f,0.f,0.f,0.f,0.f};
        const int ita = (a1 - a0 + 1) >> 1;
        const int itb = (b1 - b0 + 1) >> 1;
        const int it = (ita > itb) ? ita : itb;
        for (int i2 = 0; i2 < it; ++i2) {
            const int ea = a0 + i2 * 2 + slot;
            const int eb = b0 + i2 * 2 + slot;
            const __bf16* pa = (ea < a1) ? h + (size_t)srcs[ea] * 256 : zrow;
            const __bf16* pb = (eb < b1) ? h + (size_t)srcs[eb] * 256 : zrow;
            const bf16x8 ra = *(const bf16x8*)(pa + dl * 8);
            const bf16x8 rb = *(const bf16x8*)(pb + dl * 8);
            #pragma unroll
            for (int d = 0; d < 8; ++d) { aa[d] += (float)ra[d]; ab[d] += (float)rb[d]; }
        }
        #pragma unroll
        for (int d = 0; d < 8; ++d) {
            aa[d] += __shfl_xor(aa[d], 32);
            ab[d] += __shfl_xor(ab[d], 32);
        }
        if (slot == 0) {
            const int deg = a1 - a0;
            const float inv = 1.f / (float)(deg > 0 ? deg : 1);
            bf16x8 o;
            #pragma unroll
            for (int d = 0; d < 8; ++d) o[d] = (__bf16)(aa[d] * inv);
            *(bf16x8*)(Agg + (size_t)ga * 256 + dl * 8) = o;
        } else {
            const int deg = b1 - b0;
            const float inv = 1.f / (float)(deg > 0 ? deg : 1);
            bf16x8 o;
            #pragma unroll
            for (int d = 0; d < 8; ++d) o[d] = (__bf16)(ab[d] * inv);
            *(bf16x8*)(Agg + (size_t)gb * 256 + dl * 8) = o;
        }
    }
}

// ---------------- bf16 MFMA GEMM: C = act([A1|A2] @ W^T + bias) ----------------
template<int KHALF, int LDC, bool RELU, bool OUTBF16>
__global__ __launch_bounds__(256) void k_gemm(
    const __bf16* __restrict__ A1, const __bf16* __restrict__ A2,
    const __bf16* __restrict__ W, const float* __restrict__ bias,
    float* __restrict__ outf, __bf16* __restrict__ outb, int Mrows)
{
    const int K = KHALF * 2;
    const int tid = threadIdx.x;
    const int l = tid & 63;
    const int w = tid >> 6;
    const int wm = w & 1, wn = w >> 1;
    const int row0 = blockIdx.x * 128 + wm * 64;
    const int col0 = blockIdx.y * 128 + wn * 64;
    const int lr = l & 15;
    const int lk = (l >> 4) * 8;

    const __bf16* pa1[4];
    const __bf16* pa2[4];
    const __bf16* pb[4];
    #pragma unroll
    for (int i = 0; i < 4; ++i) {
        int r = row0 + i * 16 + lr;
        r = (r < Mrows) ? r : (Mrows - 1);
        pa1[i] = A1 + (size_t)r * KHALF + lk;
        pa2[i] = A2 + (size_t)r * KHALF + lk;
        pb[i] = W + (size_t)(col0 + i * 16 + lr) * K + lk;
    }
    f32x4 acc[4][4];
    #pragma unroll
    for (int i = 0; i < 4; ++i)
        #pragma unroll
        for (int j = 0; j < 4; ++j)
            acc[i][j] = (f32x4)0.0f;

    #pragma unroll 2
    for (int k0 = 0; k0 < KHALF; k0 += 32) {
        bf16x8 fa[4], fb[4];
        #pragma unroll
        for (int i = 0; i < 4; ++i) fa[i] = *(const bf16x8*)(pa1[i] + k0);
        #pragma unroll
        for (int j = 0; j < 4; ++j) fb[j] = *(const bf16x8*)(pb[j] + k0);
        #pragma unroll
        for (int i = 0; i < 4; ++i)
            #pragma unroll
            for (int j = 0; j < 4; ++j)
                acc[i][j] = __builtin_amdgcn_mfma_f32_16x16x32_bf16(fa[i], fb[j], acc[i][j], 0, 0, 0);
    }
    #pragma unroll 2
    for (int k0 = 0; k0 < KHALF; k0 += 32) {
        bf16x8 fa[4], fb[4];
        #pragma unroll
        for (int i = 0; i < 4; ++i) fa[i] = *(const bf16x8*)(pa2[i] + k0);
        #pragma unroll
        for (int j = 0; j < 4; ++j) fb[j] = *(const bf16x8*)(pb[j] + KHALF + k0);
        #pragma unroll
        for (int i = 0; i < 4; ++i)
            #pragma unroll
            for (int j = 0; j < 4; ++j)
                acc[i][j] = __builtin_amdgcn_mfma_f32_16x16x32_bf16(fa[i], fb[j], acc[i][j], 0, 0, 0);
    }

    // C/D layout: col = lane&15, row = (lane>>4)*4 + reg
    #pragma unroll
    for (int j = 0; j < 4; ++j) {
        const int colg = col0 + j * 16 + lr;
        const float bj = bias[colg];
        #pragma unroll
        for (int i = 0; i < 4; ++i) {
            #pragma unroll
            for (int reg = 0; reg < 4; ++reg) {
                const int rowg = row0 + i * 16 + (l >> 4) * 4 + reg;
                if (rowg < Mrows) {
                    float v = acc[i][j][reg] + bj;
                    if (RELU) v = fmaxf(v, 0.f);
                    if (OUTBF16) outb[(size_t)rowg * LDC + colg] = (__bf16)v;
                    else         outf[(size_t)rowg * LDC + colg] = v;
                }
            }
        }
    }
}

// ---------------- launch ----------------

extern "C" void kernel_launch(void* const* d_in, const int* in_sizes, int n_in,
                              void* d_out, int out_size, void* d_ws, size_t ws_size,
                              hipStream_t stream) {
    const float* x   = (const float*)d_in[0];
    const float* Wl0 = (const float*)d_in[1];
    const float* bl0 = (const float*)d_in[2];
    const float* Wr0 = (const float*)d_in[3];
    const float* Wl1 = (const float*)d_in[4];
    const float* bl1 = (const float*)d_in[5];
    const float* Wr1 = (const float*)d_in[6];
    const int* e0s = (const int*)d_in[7];
    const int* e0d = (const int*)d_in[8];
    const int* e1s = (const int*)d_in[9];
    const int* e1d = (const int*)d_in[10];
    float* out = (float*)d_out;

    char* ws = (char*)d_ws;
    size_t pos = 0;
    auto alloc = [&](size_t nb) -> void* {
        void* p = ws + pos;
        pos += (nb + 255) & ~(size_t)255;
        return p;
    };
    __bf16* xb   = (__bf16*)alloc((size_t)cN0 * 128 * 2);   // 128 MB
    __bf16* h    = (__bf16*)alloc((size_t)cN1 * 256 * 2);   // 51.2 MB
    __bf16* Agg0 = (__bf16*)alloc((size_t)cN1 * 128 * 2);   // 25.6 MB
    __bf16* Agg1 = Agg0;                                    // aliases Agg0
    // contiguous zero-init strip: bkt0 | bkt1 | zrow (single tiny memset)
    int* bkt0    = (int*)alloc(((size_t)(NB0 + 1) + (NB1 + 1) + 128) * 4);
    int* bkt1    = bkt0 + (NB0 + 1);
    __bf16* zrow = (__bf16*)(bkt1 + (NB1 + 1));
    const size_t zbytes = ((size_t)(NB0 + 1) + (NB1 + 1) + 128) * 4;
    int* bcur0   = (int*)alloc((size_t)NB0 * 4);
    int* bcur1   = (int*)alloc((size_t)NB1 * 4);
    int2* pair0  = (int2*)alloc((size_t)cE0 * 8);           // 12.8 MB
    int2* pair1  = (int2*)alloc((size_t)cE1 * 8);           // 3.2 MB
    int* off0    = (int*)alloc((size_t)(cN1 + 1) * 4);
    int* off1    = (int*)alloc((size_t)(cN2 + 1) * 4);
    int* srcs0   = (int*)alloc((size_t)cE0 * 4);
    int* srcs1   = (int*)alloc((size_t)cE1 * 4);
    int* bsum0   = (int*)alloc(128 * 4);
    int* bsum1   = (int*)alloc(128 * 4);
    __bf16* Wc0  = (__bf16*)alloc(256 * 256 * 2);
    __bf16* Wc1  = (__bf16*)alloc(128 * 512 * 2);
    (void)ws_size; (void)in_sizes; (void)n_in; (void)out_size;

    // 1. zero bucket strip (32 KB)
    hipMemsetAsync(bkt0, 0, zbytes, stream);
    // 2. fused prep: cast + bucket hists + wcat
    k_prep<<<39575, 256, 0, stream>>>(x, xb, e0d, bkt0, e1d, bkt1,
                                      Wl0, Wr0, Wc0, Wl1, Wr1, Wc1);
    // 3-5. bucket-offset scans
    k_scanA<<<9, 256, 0, stream>>>(bkt0, bsum0, bkt1, bsum1);
    k_scanB<<<2, 128, 0, stream>>>(bsum0, bsum1);
    k_scanC<<<32, 256, 0, stream>>>(bkt0, bsum0, bcur0, bkt1, bsum1, bcur1);
    // 6. pair scatter into buckets
    k_phaseB<<<7813, 256, 0, stream>>>(e0s, e0d, bcur0, pair0, e1s, e1d, bcur1, pair1);
    // 7. per-bucket CSR build
    k_phaseC<<<NB0 + NB1, 256, 0, stream>>>(bkt0, pair0, off0, srcs0,
                                            bkt1, pair1, off1, srcs1);

    // 8-9. hop 0
    k_agg0<<<3125, 256, 0, stream>>>(xb, off0, srcs0, zrow, Agg0);
    {
        dim3 grid((cN1 + 127) / 128, 2);
        k_gemm<128, 256, true, true><<<grid, 256, 0, stream>>>(Agg0, xb, Wc0, bl0, nullptr, h, cN1);
    }
    // 10-11. hop 1
    k_agg1<<<(6250 + 3) / 4, 256, 0, stream>>>(h, off1, srcs1, zrow, Agg1);
    {
        dim3 grid((cN2 + 127) / 128, 1);
        k_gemm<256, 128, false, false><<<grid, 256, 0, stream>>>(Agg1, h, Wc1, bl1, out, nullptr, cN2);
    }
}